// Round 1
// baseline (57.196 us; speedup 1.0000x reference)
//
#include <hip/hip_runtime.h>

#define RPB 128      // rows (batch elements) per block
#define XDIM 99      // floats per input row
#define NJ 26        // joints in output

__device__ __forceinline__ void rodrigues(float ax, float ay, float az, float* R) {
    const float EPS = 1.1920928955078125e-07f;   // np.finfo(np.float32).eps
    float t = sqrtf(ax*ax + ay*ay + az*az);
    float inv = 1.0f / (t + EPS);
    float r0 = ax*inv, r1 = ay*inv, r2 = az*inv;
    float s = __sinf(t);
    float c = __cosf(t);
    float omc = 1.0f - c;
    float r00 = r0*r0, r11 = r1*r1, r22 = r2*r2;
    float r01 = r0*r1, r02 = r0*r2, r12 = r1*r2;
    // R = I + s*S + (1-c)*S^2, S = [[0,-r2,r1],[r2,0,-r0],[-r1,r0,0]]
    R[0] = 1.0f - omc*(r11 + r22);
    R[1] = -s*r2 + omc*r01;
    R[2] =  s*r1 + omc*r02;
    R[3] =  s*r2 + omc*r01;
    R[4] = 1.0f - omc*(r00 + r22);
    R[5] = -s*r0 + omc*r12;
    R[6] = -s*r1 + omc*r02;
    R[7] =  s*r0 + omc*r12;
    R[8] = 1.0f - omc*(r00 + r11);
}

__global__ __launch_bounds__(RPB) void skel_fk(const float* __restrict__ x,
                                               const float* __restrict__ off,
                                               float* __restrict__ out) {
    __shared__ float lds[RPB * XDIM];
    const int tid = threadIdx.x;
    const long long row0 = (long long)blockIdx.x * RPB;

    // ---- stage x rows into LDS, fully coalesced float4 ----
    {
        const int nf4 = RPB * XDIM / 4;  // 3168
        const float4* src = reinterpret_cast<const float4*>(x + row0 * XDIM);
        float4* dst = reinterpret_cast<float4*>(lds);
        #pragma unroll
        for (int j = 0; j < (nf4 + RPB - 1) / RPB; ++j) {
            int k = tid + j * RPB;
            if (k < nf4) dst[k] = src[k];
        }
    }
    __syncthreads();

    const float* row = &lds[tid * XDIM];
    const long long gid = row0 + tid;
    float* orow = out + gid * (NJ * 3);

    // slot tables (slot 0 = hip, slots 1..25 follow ORDER)
    constexpr int OFF_IDX[NJ] = {0,1,2,3,4,6,7,8,9,11,12,13,14,15,16,17,18,19,20,22,24,25,26,27,28,30};
    constexpr int PAR[NJ]     = {-1,0,1,2,3,0,5,6,7,0,9,10,11,12,10,14,15,16,17,17,10,20,21,22,23,23};

    float ang[NJ][9];
    float px[NJ], py[NJ], pz[NJ];

    // hip
    px[0] = off[0] + row[0];
    py[0] = off[1] + row[1];
    pz[0] = off[2] + row[2];
    rodrigues(row[3], row[4], row[5], ang[0]);
    orow[0] = px[0]; orow[1] = py[0]; orow[2] = pz[0];

    #pragma unroll
    for (int s = 1; s < NJ; ++s) {
        const int i = OFF_IDX[s];
        const int p = PAR[s];
        float L[9];
        rodrigues(row[3*i+3], row[3*i+4], row[3*i+5], L);

        const float o0 = off[3*i], o1 = off[3*i+1], o2 = off[3*i+2];
        // pos[s] = offset[i] (row-vec) @ ang[p] + pos[p]
        px[s] = o0*ang[p][0] + o1*ang[p][3] + o2*ang[p][6] + px[p];
        py[s] = o0*ang[p][1] + o1*ang[p][4] + o2*ang[p][7] + py[p];
        pz[s] = o0*ang[p][2] + o1*ang[p][5] + o2*ang[p][8] + pz[p];

        // ang[s] = L @ ang[p]
        #pragma unroll
        for (int j = 0; j < 3; ++j) {
            #pragma unroll
            for (int k = 0; k < 3; ++k) {
                ang[s][3*j+k] = L[3*j+0]*ang[p][0+k]
                              + L[3*j+1]*ang[p][3+k]
                              + L[3*j+2]*ang[p][6+k];
            }
        }

        orow[s*3+0] = px[s];
        orow[s*3+1] = py[s];
        orow[s*3+2] = pz[s];
    }
}

extern "C" void kernel_launch(void* const* d_in, const int* in_sizes, int n_in,
                              void* d_out, int out_size, void* d_ws, size_t ws_size,
                              hipStream_t stream) {
    const float* x   = (const float*)d_in[0];
    const float* off = (const float*)d_in[1];
    float* out = (float*)d_out;
    const int B = in_sizes[0] / XDIM;      // 262144
    const int grid = B / RPB;              // exact: 262144 / 128 = 2048
    skel_fk<<<grid, RPB, 0, stream>>>(x, off, out);
}